// Round 1
// baseline (15599.785 us; speedup 1.0000x reference)
//
#include <hip/hip_runtime.h>

// ---------------- problem constants ----------------
#define T_SEQ 512
#define P_PRED 32
#define TP 544            // T_SEQ + P_PRED
#define BATCH 256
#define H 512
#define G4H 2048
// ---------------- kernel config --------------------
// 256 WGs = 16 row-groups x 16 col-slots, 512 threads (8 waves) each.
// grp = wg&15 owns batch rows [16g,16g+16). slot = wg>>4 owns h-cols
// [32s,32s+32); wave w owns h-cols 32s+4w..+4 (16 gate-cols). Weights in
// VGPRs (192/lane). Per phase each WG stages its group's 16-row h slices
// LIC->LDS once, MFMAs (M=16) from LDS. 8 waves = 2/SIMD -> latency
// overlap; staging LIC traffic 8 MB/phase (was 16). Cross-WG data via
// sc0|sc1 at LIC. Barrier = sense flags, 16 slots/group.
#define GRID 256
#define BLOCK 512
#define RPG 16              // rows per group
#define HBUF (BATCH*H)      // elements per h double-buffer slot
#define HBYTES (HBUF*2)
#define SC01 17             // CPol: SC0|SC1 -> bypass L1+L2, operate at LIC

typedef _Float16 half8 __attribute__((ext_vector_type(8)));
typedef float floatx4 __attribute__((ext_vector_type(4)));
typedef __amdgpu_buffer_rsrc_t rsrc_t;

#define MFMA(a,b,c) __builtin_amdgcn_mfma_f32_16x16x32_f16((a),(b),(c),0,0,0)

// ---------------- device-global state --------------
__device__ __attribute__((aligned(128))) _Float16 g_h1[2*HBUF];
__device__ __attribute__((aligned(128))) _Float16 g_h2[2*HBUF];
// o partials: [j = wg*8 + wave][t][16 group-local rows]
__device__ __attribute__((aligned(128))) float g_opart[(size_t)2048*TP*RPG];
__device__ __attribute__((aligned(128))) float g_seqT[T_SEQ*BATCH];  // [t][row]
__device__ __attribute__((aligned(128))) unsigned g_flags[16*32];    // 1 line/group

__device__ __forceinline__ rsrc_t mkrsrc(void* p){
  return __builtin_amdgcn_make_buffer_rsrc(p, (short)0, -1, 0x00020000);
}
__device__ __forceinline__ half8 ld_h8(rsrc_t r, int off){
  auto v = __builtin_amdgcn_raw_buffer_load_b128(r, off, 0, SC01);
  return __builtin_bit_cast(half8, v);
}
__device__ __forceinline__ floatx4 ld_f4(rsrc_t r, int off){
  auto v = __builtin_amdgcn_raw_buffer_load_b128(r, off, 0, SC01);
  return __builtin_bit_cast(floatx4, v);
}
__device__ __forceinline__ float ld_f(rsrc_t r, int off){
  auto v = __builtin_amdgcn_raw_buffer_load_b32(r, off, 0, SC01);
  return __builtin_bit_cast(float, v);
}
__device__ __forceinline__ void st_f(rsrc_t r, int off, float v){
  __builtin_amdgcn_raw_buffer_store_b32(__builtin_bit_cast(unsigned, v), r, off, 0, SC01);
}
__device__ __forceinline__ void st_f4(rsrc_t r, int off, floatx4 v){
  __builtin_amdgcn_raw_buffer_store_b128(v, r, off, 0, SC01);
}

__device__ __forceinline__ float sigm(float x){ return 1.0f/(1.0f + __expf(-x)); }
__device__ __forceinline__ float tanh_f(float x){ return 1.0f - 2.0f/(1.0f + __expf(2.0f*x)); }

// Sense-flag group barrier (16 slots/group). Monotone phase numbers, no RMW.
__device__ __forceinline__ void xbar(int grp, int slot, unsigned target,
                                     bool& alive, int tid){
  __builtin_amdgcn_s_waitcnt(0);
  __syncthreads();
  if (tid < 64){
    if (tid == 0)
      __hip_atomic_store(&g_flags[grp*32 + slot], target, __ATOMIC_RELAXED,
                         __HIP_MEMORY_SCOPE_AGENT);
    if (alive){
      int guard = 0;
      for (;;){
        unsigned f = __hip_atomic_load(&g_flags[grp*32 + (tid & 15)],
                                       __ATOMIC_RELAXED, __HIP_MEMORY_SCOPE_AGENT);
        if (__ballot(f >= target) == 0xFFFFFFFFFFFFFFFFull) break;
        __builtin_amdgcn_s_sleep(1);
        if (++guard > (1<<22)){ alive = false; break; }
      }
    }
  }
  __syncthreads();
}

// One pipeline phase. Stages group h slices (16 rows) LIC->LDS (swizzled),
// MFMAs (M=16) from LDS vs VGPR weights. DOL1: h1 = lstm(x, h1prev);
// XSEL 0 = x from seqT, 1 = x from o-partial gather (+bl). DOL2:
// h2 = lstm(h1r, h2prev) + o-partial line store (z2 reuses staged h1r).
template<bool DOL1, bool DOL2, int XSEL>
__device__ __forceinline__ void do_phase(
    rsrc_t rh1, rsrc_t rh2, rsrc_t rop, rsrc_t rsq,
    int o_h1r, int o_h2r, int o_h1w, int o_h2w,
    int o_x, int xs_t, float xadd, int t_out,
    _Float16* __restrict__ lA1, _Float16* __restrict__ lA2,
    const half8 (&wf1)[16], const half8 (&wfx)[16], const half8 (&wfh)[16],
    float b1, float b2, float wx, float wl,
    float (&c1v)[4], float (&c2v)[4],
    int rowbase, int grp, int wg8w, int tid, int ln, int quad, int hcb)
{
  // ---- stage A slices (16 rows x 512 fp16) from LIC into swizzled LDS ----
  {
    const int row = tid >> 5, c32 = tid & 31;
    const int gb1 = o_h1r + (rowbase + row)*H*2;
    const int gb2 = o_h2r + (rowbase + row)*H*2;
    #pragma unroll
    for (int g2 = 0; g2 < 2; ++g2){
      const int gran = c32*2 + g2;
      const int loff = row*512 + ((gran ^ (row&7)) << 3);
      half8 v = ld_h8(rh1, gb1 + gran*16);
      *(half8*)(lA1 + loff) = v;
      if (DOL2){
        half8 u = ld_h8(rh2, gb2 + gran*16);
        *(half8*)(lA2 + loff) = u;
      }
    }
  }

  float xv[4];
  if (DOL1){
    if (XSEL == 0){
      floatx4 x4 = ld_f4(rsq, o_x + (rowbase + quad*4)*4);
      #pragma unroll
      for (int r=0; r<4; ++r) xv[r] = x4[r] + xadd;
    } else {
      #pragma unroll
      for (int r=0; r<4; ++r){
        const int lr = quad*4 + r;           // group-local row
        float s = 0.f;
        #pragma unroll
        for (int cc=0; cc<8; ++cc){
          const int j = ln*128 + grp*8 + cc; // (slot'=ln, wave'=cc)
          s += ld_f(rop, ((j*TP + xs_t)*RPG + lr)*4);
        }
        s += __shfl_xor(s, 1, 64);
        s += __shfl_xor(s, 2, 64);
        s += __shfl_xor(s, 4, 64);
        s += __shfl_xor(s, 8, 64);
        xv[r] = s + xadd;
      }
    }
  }
  __syncthreads();   // staging visible WG-wide

  floatx4 zf4 = {0.f,0.f,0.f,0.f};
  floatx4 z1 = zf4, z2 = zf4;

  #pragma unroll
  for (int kk = 0; kk < 16; ++kk){
    const int sw = (((kk*4 + quad) ^ (ln&7)) << 3);
    half8 a1 = *(const half8*)(lA1 + ln*512 + sw);
    if (DOL1)
      z1 = MFMA(a1, wf1[kk], z1);
    if (DOL2){
      z2 = MFMA(a1, wfx[kk], z2);
      half8 a2 = *(const half8*)(lA2 + ln*512 + sw);
      z2 = MFMA(a2, wfh[kk], z2);
    }
  }

  const bool l4 = (ln < 4);
  const bool evn = ((ln & 1) == 0);
  if (DOL1){
    #pragma unroll
    for (int r=0; r<4; ++r){
      const int row = rowbase + quad*4 + r;
      float z = z1[r] + xv[r]*wx + b1;
      float p4  = __shfl_xor(z, 4, 64);
      float p8  = __shfl_xor(z, 8, 64);
      float p12 = __shfl_xor(z, 12, 64);
      float ig = sigm(z), fg = sigm(p4), og = sigm(p8), gg = tanh_f(p12);
      float c = fg*c1v[r] + ig*gg;
      c1v[r] = c;
      float h = og*tanh_f(c);
      unsigned hu = (unsigned)__builtin_bit_cast(unsigned short, (_Float16)h);
      unsigned pn = (unsigned)__shfl_xor((int)hu, 1, 64);
      if (l4 && evn)
        st_f(rh1, o_h1w + (row*H + hcb + ln)*2,
             __builtin_bit_cast(float, hu | (pn<<16)));
    }
  }
  if (DOL2){
    floatx4 po4;
    #pragma unroll
    for (int r=0; r<4; ++r){
      const int row = rowbase + quad*4 + r;
      float z = z2[r] + b2;
      float p4  = __shfl_xor(z, 4, 64);
      float p8  = __shfl_xor(z, 8, 64);
      float p12 = __shfl_xor(z, 12, 64);
      float ig = sigm(z), fg = sigm(p4), og = sigm(p8), gg = tanh_f(p12);
      float c = fg*c2v[r] + ig*gg;
      c2v[r] = c;
      float h = og*tanh_f(c);
      unsigned hu = (unsigned)__builtin_bit_cast(unsigned short, (_Float16)h);
      unsigned pn = (unsigned)__shfl_xor((int)hu, 1, 64);
      if (l4 && evn)
        st_f(rh2, o_h2w + (row*H + hcb + ln)*2,
             __builtin_bit_cast(float, hu | (pn<<16)));
      float po = l4 ? h*wl : 0.f;
      po += __shfl_xor(po, 1, 64);
      po += __shfl_xor(po, 2, 64);
      po4[r] = po;              // valid in ln==0 lanes
    }
    if (ln == 0){               // 64B line segment per wave per t
      const int base = ((wg8w*TP + t_out)*RPG)*4;
      st_f4(rop, base + quad*16, po4);
    }
  }
}

__global__ void reset_kernel(){
  if (threadIdx.x < 16*32)
    __hip_atomic_store(&g_flags[threadIdx.x], 0u, __ATOMIC_RELAXED,
                       __HIP_MEMORY_SCOPE_AGENT);
}

__global__ __launch_bounds__(BLOCK, 2) void sinernn_kernel(
    const float* __restrict__ seq, const float* __restrict__ Wx1,
    const float* __restrict__ bx1, const float* __restrict__ Wh1,
    const float* __restrict__ bh1, const float* __restrict__ Wx2,
    const float* __restrict__ bx2, const float* __restrict__ Wh2,
    const float* __restrict__ bh2, const float* __restrict__ Wl,
    const float* __restrict__ bl,  float* __restrict__ out)
{
  __shared__ __attribute__((aligned(16))) _Float16 lA1[RPG*512];  // 16 KB
  __shared__ __attribute__((aligned(16))) _Float16 lA2[RPG*512];  // 16 KB

  const int tid  = threadIdx.x;
  const int wg   = blockIdx.x;
  const int grp  = wg & 15;            // row group 0..15
  const int slot = wg >> 4;            // 0..15 within group
  const int w    = tid >> 6;
  const int lane = tid & 63;
  const int ln   = lane & 15;
  const int quad = lane >> 4;
  const int rowbase = grp*RPG;
  const int hcb  = slot*32 + w*4;      // this wave's 4 h-cols
  const int wg8w = wg*8 + w;           // o-partial line owner id

  rsrc_t rh1 = mkrsrc((void*)&g_h1[0]);
  rsrc_t rh2 = mkrsrc((void*)&g_h2[0]);
  rsrc_t rop = mkrsrc((void*)&g_opart[0]);
  rsrc_t rsq = mkrsrc((void*)&g_seqT[0]);

  // gate-col: gate = ln>>2, h-col = hcb + (ln&3)
  const int gc = (ln>>2)*H + hcb + (ln&3);

  // ---- prologue: seqT transpose (this WG: 32 t-values x 16 group rows) ----
  for (int i = tid; i < 32*16; i += BLOCK){
    int t = slot*32 + (i>>4), j = i & 15;
    st_f(rsq, (t*BATCH + rowbase + j)*4, seq[(rowbase+j)*T_SEQ + t]);
  }
  // zero h(-1) (buffer 1) for group rows; redundant across slots, benign
  for (int i = tid; i < RPG*H/2; i += BLOCK){
    int off = HBYTES + rowbase*H*2 + i*4;
    st_f(rh1, off, 0.f);
    st_f(rh2, off, 0.f);
  }

  // ---- stage all three weight slices into VGPRs (192/lane) ----
  half8 wf1[16], wfx[16], wfh[16];
  #pragma unroll
  for (int kk = 0; kk < 16; ++kk){
    #pragma unroll
    for (int j = 0; j < 8; ++j){
      const int k = kk*32 + quad*8 + j;
      wf1[kk][j] = (_Float16)Wh1[k*G4H + gc];
      wfx[kk][j] = (_Float16)Wx2[k*G4H + gc];
      wfh[kk][j] = (_Float16)Wh2[k*G4H + gc];
    }
  }
  const float b1 = bx1[gc] + bh1[gc];
  const float b2 = bx2[gc] + bh2[gc];
  const float wx = Wx1[gc];
  const float wl = (ln < 4) ? Wl[hcb + (ln&3)] : 0.f;
  const float blv = bl[0];

  float c1v[4] = {0.f,0.f,0.f,0.f};
  float c2v[4] = {0.f,0.f,0.f,0.f};

  unsigned bidx = 0;
  bool alive = true;
  xbar(grp, slot, ++bidx, alive, tid);   // prologue visible group-wide

  // ---- main pipelined region: phase p computes h1(p) and h2(p-1) ----
  for (int p = 0; p < T_SEQ; ++p){
    const int b_h1r = ((p+1)&1)*HBYTES;
    const int b_h1w = (p&1)*HBYTES;
    if (p == 0)
      do_phase<true,false,0>(rh1,rh2,rop,rsq, b_h1r,0, b_h1w,0,
                             0, 0, 0.f, -1, lA1, lA2, wf1,wfx,wfh,
                             b1,b2,wx,wl, c1v,c2v,
                             rowbase, grp, wg8w, tid, ln, quad, hcb);
    else
      do_phase<true,true,0>(rh1,rh2,rop,rsq, b_h1r,(p&1)*HBYTES,
                            b_h1w,((p+1)&1)*HBYTES,
                            p*BATCH*4, 0, 0.f, p-1, lA1, lA2, wf1,wfx,wfh,
                            b1,b2,wx,wl, c1v,c2v,
                            rowbase, grp, wg8w, tid, ln, quad, hcb);
    xbar(grp, slot, ++bidx, alive, tid);
  }

  // ---- drain + autoregressive predict ----
  for (int s = T_SEQ-1; s < TP; ++s){
    do_phase<false,true,0>(rh1,rh2,rop,rsq, (s&1)*HBYTES,((s+1)&1)*HBYTES,
                           0,(s&1)*HBYTES,
                           0, 0, 0.f, s, lA1, lA2, wf1,wfx,wfh,
                           b1,b2,wx,wl, c1v,c2v,
                           rowbase, grp, wg8w, tid, ln, quad, hcb);
    xbar(grp, slot, ++bidx, alive, tid);
    if (s + 1 < TP){
      do_phase<true,false,1>(rh1,rh2,rop,rsq, (s&1)*HBYTES,0,
                             ((s+1)&1)*HBYTES,0,
                             0, s, blv, -1, lA1, lA2, wf1,wfx,wfh,
                             b1,b2,wx,wl, c1v,c2v,
                             rowbase, grp, wg8w, tid, ln, quad, hcb);
      xbar(grp, slot, ++bidx, alive, tid);
    }
  }

  // ---- epilogue: out[row][t] = sum over this group's 128 (slot',w') ----
  {
    float* lred = (float*)lA1;           // reuse staging LDS
    const int row = tid & 15, part = tid >> 4;   // 32 parts
    for (int i = 0; i < 34; ++i){
      const int t = slot*34 + i;
      float s = 0.f;
      #pragma unroll
      for (int q = 0; q < 4; ++q){
        const int jj = part*4 + q;       // 0..127
        const int j  = (jj>>3)*128 + grp*8 + (jj&7);
        s += ld_f(rop, ((j*TP + t)*RPG + row)*4);
      }
      __syncthreads();
      lred[part*16 + row] = s;
      __syncthreads();
      if (tid < 16){
        float o = 0.f;
        #pragma unroll
        for (int p2 = 0; p2 < 32; ++p2) o += lred[p2*16 + tid];
        out[(rowbase + tid)*TP + t] = o + blv;
      }
    }
  }
}

extern "C" void kernel_launch(void* const* d_in, const int* in_sizes, int n_in,
                              void* d_out, int out_size, void* d_ws, size_t ws_size,
                              hipStream_t stream) {
  const float* seq = (const float*)d_in[0];
  // d_in[1] = predict (=32, hardcoded)
  const float* Wx1 = (const float*)d_in[2];
  const float* bx1 = (const float*)d_in[3];
  const float* Wh1 = (const float*)d_in[4];
  const float* bh1 = (const float*)d_in[5];
  const float* Wx2 = (const float*)d_in[6];
  const float* bx2 = (const float*)d_in[7];
  const float* Wh2 = (const float*)d_in[8];
  const float* bh2 = (const float*)d_in[9];
  const float* Wl  = (const float*)d_in[10];
  const float* bl  = (const float*)d_in[11];
  float* out = (float*)d_out;

  reset_kernel<<<1, 512, 0, stream>>>();

  sinernn_kernel<<<dim3(GRID), dim3(BLOCK), 0, stream>>>(
      seq, Wx1, bx1, Wh1, bh1, Wx2, bx2, Wh2, bh2, Wl, bl, out);
}

// Round 2
// 10467.657 us; speedup vs baseline: 1.4903x; 1.4903x over previous
//
#include <hip/hip_runtime.h>

// ---------------- problem constants ----------------
#define T_SEQ 512
#define P_PRED 32
#define TP 544            // T_SEQ + P_PRED
#define BATCH 256
#define H 512
#define G4H 2048
// ---------------- kernel config --------------------
// 128 WGs = 8 row-groups x 16 slot-pairs, 512 threads (8 waves, 2/SIMD).
// EXACT round-0 data layout: group g (wg&7) owns batch rows [32g,32g+32);
// col-slot s (0..31) owns h-cols [16s,16s+16). Merged WG pr=wg>>3 hosts
// slots {2pr,2pr+1}: wave w -> slot 2pr+(w>>2), role w&3. Weights in VGPRs
// (192/lane, per-wave identical to round-0). Per phase the WG stages the
// group's 32-row h slices LIC->LDS ONCE for both slots (halves LIC reads),
// MFMAs from LDS. Full-128B opart lines preserved. Cross-WG data via
// sc0|sc1 at LIC. Barrier = sense flags, 16 arrivals/group.
#define GRID 128
#define BLOCK 512
#define HBUF (BATCH*H)      // elements per h double-buffer slot
#define HBYTES (HBUF*2)
#define SC01 17             // CPol: SC0|SC1 -> bypass L1+L2, operate at LIC

typedef _Float16 half8 __attribute__((ext_vector_type(8)));
typedef float floatx4 __attribute__((ext_vector_type(4)));
typedef __amdgpu_buffer_rsrc_t rsrc_t;

#define MFMA(a,b,c) __builtin_amdgcn_mfma_f32_16x16x32_f16((a),(b),(c),0,0,0)

// ---------------- device-global state --------------
__device__ __attribute__((aligned(128))) _Float16 g_h1[2*HBUF];
__device__ __attribute__((aligned(128))) _Float16 g_h2[2*HBUF];
// o partials: [j = (grp+8*slot)*4 + role][t][32 group-local rows]
__device__ __attribute__((aligned(128))) float g_opart[(size_t)1024*TP*32];
__device__ __attribute__((aligned(128))) float g_seqT[T_SEQ*BATCH];  // [t][row]
__device__ __attribute__((aligned(128))) unsigned g_flags[8*32];     // 1 line/group

__device__ __forceinline__ rsrc_t mkrsrc(void* p){
  return __builtin_amdgcn_make_buffer_rsrc(p, (short)0, -1, 0x00020000);
}
__device__ __forceinline__ half8 ld_h8(rsrc_t r, int off){
  auto v = __builtin_amdgcn_raw_buffer_load_b128(r, off, 0, SC01);
  return __builtin_bit_cast(half8, v);
}
__device__ __forceinline__ floatx4 ld_f4(rsrc_t r, int off){
  auto v = __builtin_amdgcn_raw_buffer_load_b128(r, off, 0, SC01);
  return __builtin_bit_cast(floatx4, v);
}
__device__ __forceinline__ float ld_f(rsrc_t r, int off){
  auto v = __builtin_amdgcn_raw_buffer_load_b32(r, off, 0, SC01);
  return __builtin_bit_cast(float, v);
}
__device__ __forceinline__ void st_f(rsrc_t r, int off, float v){
  __builtin_amdgcn_raw_buffer_store_b32(__builtin_bit_cast(unsigned, v), r, off, 0, SC01);
}
__device__ __forceinline__ void st_f4(rsrc_t r, int off, floatx4 v){
  __builtin_amdgcn_raw_buffer_store_b128(v, r, off, 0, SC01);
}

__device__ __forceinline__ float sigm(float x){ return 1.0f/(1.0f + __expf(-x)); }
__device__ __forceinline__ float tanh_f(float x){ return 1.0f - 2.0f/(1.0f + __expf(2.0f*x)); }

// Sense-flag group barrier (16 arrivals/group). Monotone phase numbers, no RMW.
__device__ __forceinline__ void xbar(int grp, int pr, unsigned target,
                                     bool& alive, int tid){
  __builtin_amdgcn_s_waitcnt(0);
  __syncthreads();
  if (tid < 64){
    if (tid == 0)
      __hip_atomic_store(&g_flags[grp*32 + pr], target, __ATOMIC_RELAXED,
                         __HIP_MEMORY_SCOPE_AGENT);
    if (alive){
      int guard = 0;
      for (;;){
        unsigned f = __hip_atomic_load(&g_flags[grp*32 + (tid & 15)],
                                       __ATOMIC_RELAXED, __HIP_MEMORY_SCOPE_AGENT);
        if (__ballot(f >= target) == 0xFFFFFFFFFFFFFFFFull) break;
        __builtin_amdgcn_s_sleep(1);
        if (++guard > (1<<22)){ alive = false; break; }
      }
    }
  }
  __syncthreads();
}

// One pipeline phase. Stages group h slices (32 rows) LIC->LDS (swizzled),
// MFMAs from LDS vs VGPR weights. DOL1: h1 = lstm(x, h1prev); XSEL 0 = x
// from seqT, 1 = x from o-partial gather (+bl). DOL2: h2 = lstm(h1r, h2prev)
// + full-line o-partial store (z2 reuses the staged h1r fragments).
template<bool DOL1, bool DOL2, int XSEL>
__device__ __forceinline__ void do_phase(
    rsrc_t rh1, rsrc_t rh2, rsrc_t rop, rsrc_t rsq,
    int o_h1r, int o_h2r, int o_h1w, int o_h2w,
    int o_x, int xs_t, float xadd, int t_out,
    _Float16* __restrict__ lA1, _Float16* __restrict__ lA2,
    const half8 (&wf1)[16], const half8 (&wfx)[16], const half8 (&wfh)[16],
    float b1, float b2, float wx, float wl,
    float (&c1v)[2][4], float (&c2v)[2][4],
    int rowbase, int grp, int wg4w, int tid, int ln, int quad, int hcb)
{
  // ---- stage A slices (32 rows x 512 fp16) from LIC into swizzled LDS ----
  // 512 threads: row = tid>>4 (0..31), each lane owns a contiguous 64B block.
  {
    const int row = tid >> 4, c16 = tid & 15;
    const int gb1 = o_h1r + (rowbase + row)*H*2;
    const int gb2 = o_h2r + (rowbase + row)*H*2;
    #pragma unroll
    for (int g4 = 0; g4 < 4; ++g4){
      const int gran = c16*4 + g4;
      const int loff = row*512 + ((gran ^ (row&7)) << 3);
      half8 v = ld_h8(rh1, gb1 + gran*16);
      *(half8*)(lA1 + loff) = v;
      if (DOL2){
        half8 u = ld_h8(rh2, gb2 + gran*16);
        *(half8*)(lA2 + loff) = u;
      }
    }
  }

  float xv[2][4];
  if (DOL1){
    #pragma unroll
    for (int mt=0; mt<2; ++mt){
      if (XSEL == 0){
        floatx4 x4 = ld_f4(rsq, o_x + (rowbase + mt*16 + quad*4)*4);
        #pragma unroll
        for (int r=0; r<4; ++r) xv[mt][r] = x4[r] + xadd;
      } else {
        #pragma unroll
        for (int r=0; r<4; ++r){
          const int lr = mt*16 + quad*4 + r;   // group-local row
          float s = 0.f;
          #pragma unroll
          for (int cc=0; cc<8; ++cc){
            const int jj = ln*8 + cc;          // 0..127 over (slot',role')
            const int j  = ((jj>>2)*8 + grp)*4 + (jj&3);
            s += ld_f(rop, ((j*TP + xs_t)*32 + lr)*4);
          }
          s += __shfl_xor(s, 1, 64);
          s += __shfl_xor(s, 2, 64);
          s += __shfl_xor(s, 4, 64);
          s += __shfl_xor(s, 8, 64);
          xv[mt][r] = s + xadd;
        }
      }
    }
  }
  __syncthreads();   // staging visible WG-wide

  floatx4 z1[2], z2[2];
  floatx4 zf4 = {0.f,0.f,0.f,0.f};
  z1[0]=zf4; z1[1]=zf4; z2[0]=zf4; z2[1]=zf4;

  #pragma unroll
  for (int kk = 0; kk < 16; ++kk){
    const int sw = (((kk*4 + quad) ^ (ln&7)) << 3);
    half8 a10 = *(const half8*)(lA1 + ln*512 + sw);
    half8 a11 = *(const half8*)(lA1 + (16+ln)*512 + sw);
    if (DOL1){
      z1[0] = MFMA(a10, wf1[kk], z1[0]);
      z1[1] = MFMA(a11, wf1[kk], z1[1]);
    }
    if (DOL2){
      z2[0] = MFMA(a10, wfx[kk], z2[0]);
      z2[1] = MFMA(a11, wfx[kk], z2[1]);
      half8 a20 = *(const half8*)(lA2 + ln*512 + sw);
      half8 a21 = *(const half8*)(lA2 + (16+ln)*512 + sw);
      z2[0] = MFMA(a20, wfh[kk], z2[0]);
      z2[1] = MFMA(a21, wfh[kk], z2[1]);
    }
  }

  const bool l4 = (ln < 4);
  const bool evn = ((ln & 1) == 0);
  if (DOL1){
    #pragma unroll
    for (int mt=0; mt<2; ++mt){
      #pragma unroll
      for (int r=0; r<4; ++r){
        const int row = rowbase + mt*16 + quad*4 + r;
        float z = z1[mt][r] + xv[mt][r]*wx + b1;
        float p4  = __shfl_xor(z, 4, 64);
        float p8  = __shfl_xor(z, 8, 64);
        float p12 = __shfl_xor(z, 12, 64);
        float ig = sigm(z), fg = sigm(p4), og = sigm(p8), gg = tanh_f(p12);
        float c = fg*c1v[mt][r] + ig*gg;
        c1v[mt][r] = c;
        float h = og*tanh_f(c);
        unsigned hu = (unsigned)__builtin_bit_cast(unsigned short, (_Float16)h);
        unsigned pn = (unsigned)__shfl_xor((int)hu, 1, 64);
        if (l4 && evn)
          st_f(rh1, o_h1w + (row*H + hcb + ln)*2,
               __builtin_bit_cast(float, hu | (pn<<16)));
      }
    }
  }
  if (DOL2){
    floatx4 po4[2];
    #pragma unroll
    for (int mt=0; mt<2; ++mt){
      #pragma unroll
      for (int r=0; r<4; ++r){
        const int row = rowbase + mt*16 + quad*4 + r;
        float z = z2[mt][r] + b2;
        float p4  = __shfl_xor(z, 4, 64);
        float p8  = __shfl_xor(z, 8, 64);
        float p12 = __shfl_xor(z, 12, 64);
        float ig = sigm(z), fg = sigm(p4), og = sigm(p8), gg = tanh_f(p12);
        float c = fg*c2v[mt][r] + ig*gg;
        c2v[mt][r] = c;
        float h = og*tanh_f(c);
        unsigned hu = (unsigned)__builtin_bit_cast(unsigned short, (_Float16)h);
        unsigned pn = (unsigned)__shfl_xor((int)hu, 1, 64);
        if (l4 && evn)
          st_f(rh2, o_h2w + (row*H + hcb + ln)*2,
               __builtin_bit_cast(float, hu | (pn<<16)));
        float po = l4 ? h*wl : 0.f;
        po += __shfl_xor(po, 1, 64);
        po += __shfl_xor(po, 2, 64);
        po4[mt][r] = po;              // valid in ln==0 lanes
      }
    }
    if (ln == 0){                     // full 128B line per wave per t
      const int base = ((wg4w*TP + t_out)*32)*4;
      st_f4(rop, base + quad*16, po4[0]);
      st_f4(rop, base + 64 + quad*16, po4[1]);
    }
  }
}

__global__ void reset_kernel(){
  if (threadIdx.x < 8*32)
    __hip_atomic_store(&g_flags[threadIdx.x], 0u, __ATOMIC_RELAXED,
                       __HIP_MEMORY_SCOPE_AGENT);
}

__global__ __launch_bounds__(BLOCK, 2) void sinernn_kernel(
    const float* __restrict__ seq, const float* __restrict__ Wx1,
    const float* __restrict__ bx1, const float* __restrict__ Wh1,
    const float* __restrict__ bh1, const float* __restrict__ Wx2,
    const float* __restrict__ bx2, const float* __restrict__ Wh2,
    const float* __restrict__ bh2, const float* __restrict__ Wl,
    const float* __restrict__ bl,  float* __restrict__ out)
{
  __shared__ __attribute__((aligned(16))) _Float16 lA1[32*512];  // 32 KB
  __shared__ __attribute__((aligned(16))) _Float16 lA2[32*512];  // 32 KB

  const int tid  = threadIdx.x;
  const int wg   = blockIdx.x;
  const int grp  = wg & 7;             // row group 0..7
  const int pr   = wg >> 3;            // slot-pair 0..15
  const int w    = tid >> 6;           // wave 0..7
  const int lane = tid & 63;
  const int ln   = lane & 15;
  const int quad = lane >> 4;
  const int slot = pr*2 + (w>>2);      // 0..31 (round-0 slot id)
  const int wsub = w & 3;              // round-0 wave role
  const int rowbase = grp*32;
  const int hcb  = slot*16 + wsub*4;   // this wave's 4 h-cols
  const int wg4w = (grp + 8*slot)*4 + wsub;  // round-0 o-partial line owner

  rsrc_t rh1 = mkrsrc((void*)&g_h1[0]);
  rsrc_t rh2 = mkrsrc((void*)&g_h2[0]);
  rsrc_t rop = mkrsrc((void*)&g_opart[0]);
  rsrc_t rsq = mkrsrc((void*)&g_seqT[0]);

  // gate-col: gate = ln>>2, h-col = hcb + (ln&3)
  const int gc = (ln>>2)*H + hcb + (ln&3);

  // ---- prologue: seqT transpose (this WG: 32 t-values x group rows) ----
  for (int i = tid; i < 32*32; i += BLOCK){
    int t = pr*32 + (i>>5), j = i & 31;
    st_f(rsq, (t*BATCH + rowbase + j)*4, seq[(rowbase+j)*T_SEQ + t]);
  }
  // zero h(-1) (buffer 1) for group rows; redundant across pairs, benign
  for (int i = tid; i < 32*H/2; i += BLOCK){
    int off = HBYTES + rowbase*H*2 + i*4;
    st_f(rh1, off, 0.f);
    st_f(rh2, off, 0.f);
  }

  // ---- stage all three weight slices into VGPRs (192/lane) ----
  half8 wf1[16], wfx[16], wfh[16];
  #pragma unroll
  for (int kk = 0; kk < 16; ++kk){
    #pragma unroll
    for (int j = 0; j < 8; ++j){
      const int k = kk*32 + quad*8 + j;
      wf1[kk][j] = (_Float16)Wh1[k*G4H + gc];
      wfx[kk][j] = (_Float16)Wx2[k*G4H + gc];
      wfh[kk][j] = (_Float16)Wh2[k*G4H + gc];
    }
  }
  const float b1 = bx1[gc] + bh1[gc];
  const float b2 = bx2[gc] + bh2[gc];
  const float wx = Wx1[gc];
  const float wl = (ln < 4) ? Wl[hcb + (ln&3)] : 0.f;
  const float blv = bl[0];

  float c1v[2][4] = {{0.f,0.f,0.f,0.f},{0.f,0.f,0.f,0.f}};
  float c2v[2][4] = {{0.f,0.f,0.f,0.f},{0.f,0.f,0.f,0.f}};

  unsigned bidx = 0;
  bool alive = true;
  xbar(grp, pr, ++bidx, alive, tid);   // prologue visible group-wide

  // ---- main pipelined region: phase p computes h1(p) and h2(p-1) ----
  for (int p = 0; p < T_SEQ; ++p){
    const int b_h1r = ((p+1)&1)*HBYTES;
    const int b_h1w = (p&1)*HBYTES;
    if (p == 0)
      do_phase<true,false,0>(rh1,rh2,rop,rsq, b_h1r,0, b_h1w,0,
                             0, 0, 0.f, -1, lA1, lA2, wf1,wfx,wfh,
                             b1,b2,wx,wl, c1v,c2v,
                             rowbase, grp, wg4w, tid, ln, quad, hcb);
    else
      do_phase<true,true,0>(rh1,rh2,rop,rsq, b_h1r,(p&1)*HBYTES,
                            b_h1w,((p+1)&1)*HBYTES,
                            p*BATCH*4, 0, 0.f, p-1, lA1, lA2, wf1,wfx,wfh,
                            b1,b2,wx,wl, c1v,c2v,
                            rowbase, grp, wg4w, tid, ln, quad, hcb);
    xbar(grp, pr, ++bidx, alive, tid);
  }

  // ---- drain + autoregressive predict ----
  for (int s = T_SEQ-1; s < TP; ++s){
    do_phase<false,true,0>(rh1,rh2,rop,rsq, (s&1)*HBYTES,((s+1)&1)*HBYTES,
                           0,(s&1)*HBYTES,
                           0, 0, 0.f, s, lA1, lA2, wf1,wfx,wfh,
                           b1,b2,wx,wl, c1v,c2v,
                           rowbase, grp, wg4w, tid, ln, quad, hcb);
    xbar(grp, pr, ++bidx, alive, tid);
    if (s + 1 < TP){
      do_phase<true,false,1>(rh1,rh2,rop,rsq, (s&1)*HBYTES,0,
                             ((s+1)&1)*HBYTES,0,
                             0, s, blv, -1, lA1, lA2, wf1,wfx,wfh,
                             b1,b2,wx,wl, c1v,c2v,
                             rowbase, grp, wg4w, tid, ln, quad, hcb);
      xbar(grp, pr, ++bidx, alive, tid);
    }
  }

  // ---- epilogue: out[row][t] = sum over this group's 128 (slot',role') ----
  {
    float* lred = (float*)lA1;           // reuse staging LDS
    const int row = tid & 31, part = tid >> 5;   // 16 parts
    for (int i = 0; i < 34; ++i){
      const int t = pr + i*16;
      float s = 0.f;
      #pragma unroll
      for (int q = 0; q < 8; ++q){
        const int jj = part*8 + q;       // 0..127
        const int j  = ((jj>>2)*8 + grp)*4 + (jj&3);
        s += ld_f(rop, ((j*TP + t)*32 + row)*4);
      }
      __syncthreads();
      lred[part*32 + row] = s;
      __syncthreads();
      if (tid < 32){
        float o = 0.f;
        #pragma unroll
        for (int p2 = 0; p2 < 16; ++p2) o += lred[p2*32 + tid];
        out[(rowbase + tid)*TP + t] = o + blv;
      }
    }
  }
}

extern "C" void kernel_launch(void* const* d_in, const int* in_sizes, int n_in,
                              void* d_out, int out_size, void* d_ws, size_t ws_size,
                              hipStream_t stream) {
  const float* seq = (const float*)d_in[0];
  // d_in[1] = predict (=32, hardcoded)
  const float* Wx1 = (const float*)d_in[2];
  const float* bx1 = (const float*)d_in[3];
  const float* Wh1 = (const float*)d_in[4];
  const float* bh1 = (const float*)d_in[5];
  const float* Wx2 = (const float*)d_in[6];
  const float* bx2 = (const float*)d_in[7];
  const float* Wh2 = (const float*)d_in[8];
  const float* bh2 = (const float*)d_in[9];
  const float* Wl  = (const float*)d_in[10];
  const float* bl  = (const float*)d_in[11];
  float* out = (float*)d_out;

  reset_kernel<<<1, 256, 0, stream>>>();

  sinernn_kernel<<<dim3(GRID), dim3(BLOCK), 0, stream>>>(
      seq, Wx1, bx1, Wh1, bh1, Wx2, bx2, Wh2, bh2, Wl, bl, out);
}

// Round 3
// 7650.521 us; speedup vs baseline: 2.0390x; 1.3682x over previous
//
#include <hip/hip_runtime.h>

// ---------------- problem constants ----------------
#define T_SEQ 512
#define P_PRED 32
#define TP 544            // T_SEQ + P_PRED
#define BATCH 256
#define H 512
#define G4H 2048
// ---------------- kernel config --------------------
// ROUND-0 layout, byte-for-byte: 256 WGs = 8 row-groups x 32 col-slots.
// group = blockIdx&7 owns batch rows [32g,32g+32). Slot s owns h-cols
// [16s,16s+16); wave w owns h-cols 16s+4w..+4 (16 gate-cols). Weights in
// VGPRs (192/lane). Per phase each WG stages its group's h slices LIC->LDS
// once, MFMAs from LDS. Cross-WG data via sc0|sc1 at LIC.
// ROUND-3 change (barrier path only): split xbar into xsignal (drain h +
// flag store) and xwait (ALL waves poll, no trailing syncthreads); main-loop
// opart store moved AFTER the flag (drain covered by next phase's waitcnt;
// consumed only at epilogue). Addresses/line geometry untouched.
#define GRID 256
#define BLOCK 256
#define HBUF (BATCH*H)      // elements per h double-buffer slot
#define HBYTES (HBUF*2)
#define SC01 17             // CPol: SC0|SC1 -> bypass L1+L2, operate at LIC

typedef _Float16 half8 __attribute__((ext_vector_type(8)));
typedef float floatx4 __attribute__((ext_vector_type(4)));
typedef __amdgpu_buffer_rsrc_t rsrc_t;

#define MFMA(a,b,c) __builtin_amdgcn_mfma_f32_16x16x32_f16((a),(b),(c),0,0,0)

// ---------------- device-global state --------------
__device__ __attribute__((aligned(128))) _Float16 g_h1[2*HBUF];
__device__ __attribute__((aligned(128))) _Float16 g_h2[2*HBUF];
// o partials: [j = wg*4 + wave][t][32 group-local rows] -> full-line writes
__device__ __attribute__((aligned(128))) float g_opart[(size_t)1024*TP*32];
__device__ __attribute__((aligned(128))) float g_seqT[T_SEQ*BATCH];  // [t][row]
__device__ __attribute__((aligned(128))) unsigned g_flags[8*32];     // 1 line/group

__device__ __forceinline__ rsrc_t mkrsrc(void* p){
  return __builtin_amdgcn_make_buffer_rsrc(p, (short)0, -1, 0x00020000);
}
__device__ __forceinline__ half8 ld_h8(rsrc_t r, int off){
  auto v = __builtin_amdgcn_raw_buffer_load_b128(r, off, 0, SC01);
  return __builtin_bit_cast(half8, v);
}
__device__ __forceinline__ floatx4 ld_f4(rsrc_t r, int off){
  auto v = __builtin_amdgcn_raw_buffer_load_b128(r, off, 0, SC01);
  return __builtin_bit_cast(floatx4, v);
}
__device__ __forceinline__ float ld_f(rsrc_t r, int off){
  auto v = __builtin_amdgcn_raw_buffer_load_b32(r, off, 0, SC01);
  return __builtin_bit_cast(float, v);
}
__device__ __forceinline__ void st_f(rsrc_t r, int off, float v){
  __builtin_amdgcn_raw_buffer_store_b32(__builtin_bit_cast(unsigned, v), r, off, 0, SC01);
}
__device__ __forceinline__ void st_f4(rsrc_t r, int off, floatx4 v){
  __builtin_amdgcn_raw_buffer_store_b128(v, r, off, 0, SC01);
}

__device__ __forceinline__ float sigm(float x){ return 1.0f/(1.0f + __expf(-x)); }
__device__ __forceinline__ float tanh_f(float x){ return 1.0f - 2.0f/(1.0f + __expf(2.0f*x)); }

// Release half of the group barrier: drain this wave's h stores (and any
// earlier stores), rendezvous all waves (orders all LDS reads + all waves'
// drains before the flag), then wave-0 lane-0 publishes the phase number.
__device__ __forceinline__ void xsignal(int grp, int slot, unsigned target,
                                        int tid){
  __builtin_amdgcn_s_waitcnt(0);
  __syncthreads();
  if (tid == 0)
    __hip_atomic_store(&g_flags[grp*32 + slot], target, __ATOMIC_RELAXED,
                       __HIP_MEMORY_SCOPE_AGENT);
}

// Acquire half: EVERY wave polls the group's 32-flag line (lane&31) until
// all slots reached target. No trailing __syncthreads: a wave passing here
// may start staging LDS for the next phase; all other waves already retired
// their LDS reads at xsignal's __syncthreads. Monotone phases, no reset.
__device__ __forceinline__ void xwait(int grp, unsigned target, bool& alive,
                                      int lane){
  if (!alive) return;
  int guard = 0;
  for (;;){
    unsigned f = __hip_atomic_load(&g_flags[grp*32 + (lane & 31)],
                                   __ATOMIC_RELAXED, __HIP_MEMORY_SCOPE_AGENT);
    if (__ballot(f >= target) == 0xFFFFFFFFFFFFFFFFull) break;
    if (++guard > (1<<22)){ alive = false; break; }
    __builtin_amdgcn_s_sleep(1);
  }
}

// One pipeline phase. Stages group h slices LIC->LDS (swizzled), MFMAs from
// LDS vs VGPR weights. DOL1: h1 = lstm(x, h1prev); XSEL 0 = x from seqT,
// 1 = x from o-partial gather (+bl). DOL2: h2 = lstm(h1r, h2prev); o-partials
// returned in po4o (ln==0 lanes). LATEOP: store o-partials inside (before
// drain -> flag-covered); else caller stores them after the flag.
template<bool DOL1, bool DOL2, int XSEL, bool LATEOP>
__device__ __forceinline__ void do_phase(
    rsrc_t rh1, rsrc_t rh2, rsrc_t rop, rsrc_t rsq,
    int o_h1r, int o_h2r, int o_h1w, int o_h2w,
    int o_x, int xs_t, float xadd, int t_out,
    _Float16* __restrict__ lA1, _Float16* __restrict__ lA2,
    const half8 (&wf1)[16], const half8 (&wfx)[16], const half8 (&wfh)[16],
    float b1, float b2, float wx, float wl,
    float (&c1v)[2][4], float (&c2v)[2][4], floatx4 (&po4o)[2],
    int rowbase, int grp, int wg4w, int tid, int ln, int quad, int hcb)
{
  // ---- stage A slices (32 rows x 512 fp16) from LIC into swizzled LDS ----
  {
    const int row = tid >> 3, c8 = tid & 7;
    const int gb1 = o_h1r + (rowbase + row)*H*2;
    const int gb2 = o_h2r + (rowbase + row)*H*2;
    #pragma unroll
    for (int g8 = 0; g8 < 8; ++g8){
      const int gran = c8*8 + g8;
      const int loff = row*512 + ((gran ^ (row&7)) << 3);
      half8 v = ld_h8(rh1, gb1 + gran*16);
      *(half8*)(lA1 + loff) = v;
      if (DOL2){
        half8 u = ld_h8(rh2, gb2 + gran*16);
        *(half8*)(lA2 + loff) = u;
      }
    }
  }

  float xv[2][4];
  if (DOL1){
    #pragma unroll
    for (int mt=0; mt<2; ++mt){
      if (XSEL == 0){
        floatx4 x4 = ld_f4(rsq, o_x + (rowbase + mt*16 + quad*4)*4);
        #pragma unroll
        for (int r=0; r<4; ++r) xv[mt][r] = x4[r] + xadd;
      } else {
        #pragma unroll
        for (int r=0; r<4; ++r){
          const int lr = mt*16 + quad*4 + r;   // group-local row
          float s = 0.f;
          #pragma unroll
          for (int cc=0; cc<8; ++cc){
            const int jj = ln*8 + cc;          // 0..127 over (slot',w')
            const int j  = ((jj>>2)*8 + grp)*4 + (jj&3);
            s += ld_f(rop, ((j*TP + xs_t)*32 + lr)*4);
          }
          s += __shfl_xor(s, 1, 64);
          s += __shfl_xor(s, 2, 64);
          s += __shfl_xor(s, 4, 64);
          s += __shfl_xor(s, 8, 64);
          xv[mt][r] = s + xadd;
        }
      }
    }
  }
  __syncthreads();   // staging visible WG-wide

  floatx4 z1[2], z2[2];
  floatx4 zf4 = {0.f,0.f,0.f,0.f};
  z1[0]=zf4; z1[1]=zf4; z2[0]=zf4; z2[1]=zf4;

  #pragma unroll
  for (int kk = 0; kk < 16; ++kk){
    const int sw = (((kk*4 + quad) ^ (ln&7)) << 3);
    half8 a10 = *(const half8*)(lA1 + ln*512 + sw);
    half8 a11 = *(const half8*)(lA1 + (16+ln)*512 + sw);
    if (DOL1){
      z1[0] = MFMA(a10, wf1[kk], z1[0]);
      z1[1] = MFMA(a11, wf1[kk], z1[1]);
    }
    if (DOL2){
      z2[0] = MFMA(a10, wfx[kk], z2[0]);
      z2[1] = MFMA(a11, wfx[kk], z2[1]);
      half8 a20 = *(const half8*)(lA2 + ln*512 + sw);
      half8 a21 = *(const half8*)(lA2 + (16+ln)*512 + sw);
      z2[0] = MFMA(a20, wfh[kk], z2[0]);
      z2[1] = MFMA(a21, wfh[kk], z2[1]);
    }
  }

  const bool l4 = (ln < 4);
  const bool evn = ((ln & 1) == 0);
  if (DOL1){
    #pragma unroll
    for (int mt=0; mt<2; ++mt){
      #pragma unroll
      for (int r=0; r<4; ++r){
        const int row = rowbase + mt*16 + quad*4 + r;
        float z = z1[mt][r] + xv[mt][r]*wx + b1;
        float p4  = __shfl_xor(z, 4, 64);
        float p8  = __shfl_xor(z, 8, 64);
        float p12 = __shfl_xor(z, 12, 64);
        float ig = sigm(z), fg = sigm(p4), og = sigm(p8), gg = tanh_f(p12);
        float c = fg*c1v[mt][r] + ig*gg;
        c1v[mt][r] = c;
        float h = og*tanh_f(c);
        unsigned hu = (unsigned)__builtin_bit_cast(unsigned short, (_Float16)h);
        unsigned pn = (unsigned)__shfl_xor((int)hu, 1, 64);
        if (l4 && evn)
          st_f(rh1, o_h1w + (row*H + hcb + ln)*2,
               __builtin_bit_cast(float, hu | (pn<<16)));
      }
    }
  }
  if (DOL2){
    #pragma unroll
    for (int mt=0; mt<2; ++mt){
      #pragma unroll
      for (int r=0; r<4; ++r){
        const int row = rowbase + mt*16 + quad*4 + r;
        float z = z2[mt][r] + b2;
        float p4  = __shfl_xor(z, 4, 64);
        float p8  = __shfl_xor(z, 8, 64);
        float p12 = __shfl_xor(z, 12, 64);
        float ig = sigm(z), fg = sigm(p4), og = sigm(p8), gg = tanh_f(p12);
        float c = fg*c2v[mt][r] + ig*gg;
        c2v[mt][r] = c;
        float h = og*tanh_f(c);
        unsigned hu = (unsigned)__builtin_bit_cast(unsigned short, (_Float16)h);
        unsigned pn = (unsigned)__shfl_xor((int)hu, 1, 64);
        if (l4 && evn)
          st_f(rh2, o_h2w + (row*H + hcb + ln)*2,
               __builtin_bit_cast(float, hu | (pn<<16)));
        float po = l4 ? h*wl : 0.f;
        po += __shfl_xor(po, 1, 64);
        po += __shfl_xor(po, 2, 64);
        po4o[mt][r] = po;             // valid in ln==0 lanes
      }
    }
    if (LATEOP && ln == 0){           // flag-covered opart store
      const int base = ((wg4w*TP + t_out)*32)*4;
      st_f4(rop, base + quad*16, po4o[0]);
      st_f4(rop, base + 64 + quad*16, po4o[1]);
    }
  }
}

__global__ void reset_kernel(){
  if (threadIdx.x < 8*32)
    __hip_atomic_store(&g_flags[threadIdx.x], 0u, __ATOMIC_RELAXED,
                       __HIP_MEMORY_SCOPE_AGENT);
}

__global__ __launch_bounds__(BLOCK, 1) void sinernn_kernel(
    const float* __restrict__ seq, const float* __restrict__ Wx1,
    const float* __restrict__ bx1, const float* __restrict__ Wh1,
    const float* __restrict__ bh1, const float* __restrict__ Wx2,
    const float* __restrict__ bx2, const float* __restrict__ Wh2,
    const float* __restrict__ bh2, const float* __restrict__ Wl,
    const float* __restrict__ bl,  float* __restrict__ out)
{
  __shared__ __attribute__((aligned(16))) _Float16 lA1[32*512];  // 32 KB
  __shared__ __attribute__((aligned(16))) _Float16 lA2[32*512];  // 32 KB

  const int tid  = threadIdx.x;
  const int wg   = blockIdx.x;
  const int grp  = wg & 7;             // row group 0..7
  const int slot = wg >> 3;            // 0..31 within group
  const int w    = tid >> 6;
  const int lane = tid & 63;
  const int ln   = lane & 15;
  const int quad = lane >> 4;
  const int rowbase = grp*32;
  const int hcb  = slot*16 + w*4;      // this wave's 4 h-cols
  const int wg4w = wg*4 + w;           // o-partial line owner id

  rsrc_t rh1 = mkrsrc((void*)&g_h1[0]);
  rsrc_t rh2 = mkrsrc((void*)&g_h2[0]);
  rsrc_t rop = mkrsrc((void*)&g_opart[0]);
  rsrc_t rsq = mkrsrc((void*)&g_seqT[0]);

  // gate-col: gate = ln>>2, h-col = hcb + (ln&3)
  const int gc = (ln>>2)*H + hcb + (ln&3);

  // ---- prologue: seqT transpose (this WG: 16 t-values x group rows) ----
  for (int i = tid; i < 16*32; i += BLOCK){
    int t = slot*16 + (i>>5), j = i & 31;
    st_f(rsq, (t*BATCH + rowbase + j)*4, seq[(rowbase+j)*T_SEQ + t]);
  }
  // zero h(-1) (buffer 1) for group rows; redundant across slots, benign
  for (int i = tid; i < 32*H/2; i += BLOCK){
    int off = HBYTES + rowbase*H*2 + i*4;
    st_f(rh1, off, 0.f);
    st_f(rh2, off, 0.f);
  }

  // ---- stage all three weight slices into VGPRs (192/lane) ----
  half8 wf1[16], wfx[16], wfh[16];
  #pragma unroll
  for (int kk = 0; kk < 16; ++kk){
    #pragma unroll
    for (int j = 0; j < 8; ++j){
      const int k = kk*32 + quad*8 + j;
      wf1[kk][j] = (_Float16)Wh1[k*G4H + gc];
      wfx[kk][j] = (_Float16)Wx2[k*G4H + gc];
      wfh[kk][j] = (_Float16)Wh2[k*G4H + gc];
    }
  }
  const float b1 = bx1[gc] + bh1[gc];
  const float b2 = bx2[gc] + bh2[gc];
  const float wx = Wx1[gc];
  const float wl = (ln < 4) ? Wl[hcb + (ln&3)] : 0.f;
  const float blv = bl[0];

  float c1v[2][4] = {{0.f,0.f,0.f,0.f},{0.f,0.f,0.f,0.f}};
  float c2v[2][4] = {{0.f,0.f,0.f,0.f},{0.f,0.f,0.f,0.f}};
  floatx4 po4[2];

  unsigned bidx = 0;
  bool alive = true;
  ++bidx; xsignal(grp, slot, bidx, tid);   // prologue visible group-wide
  xwait(grp, bidx, alive, lane);

  // ---- main pipelined region: phase p computes h1(p) and h2(p-1) ----
  for (int p = 0; p < T_SEQ; ++p){
    const int b_h1r = ((p+1)&1)*HBYTES;
    const int b_h1w = (p&1)*HBYTES;
    if (p == 0){
      do_phase<true,false,0,false>(rh1,rh2,rop,rsq, b_h1r,0, b_h1w,0,
                             0, 0, 0.f, -1, lA1, lA2, wf1,wfx,wfh,
                             b1,b2,wx,wl, c1v,c2v, po4,
                             rowbase, grp, wg4w, tid, ln, quad, hcb);
      ++bidx; xsignal(grp, slot, bidx, tid);
      xwait(grp, bidx, alive, lane);
    } else {
      do_phase<true,true,0,false>(rh1,rh2,rop,rsq, b_h1r,(p&1)*HBYTES,
                            b_h1w,((p+1)&1)*HBYTES,
                            p*BATCH*4, 0, 0.f, p-1, lA1, lA2, wf1,wfx,wfh,
                            b1,b2,wx,wl, c1v,c2v, po4,
                            rowbase, grp, wg4w, tid, ln, quad, hcb);
      ++bidx; xsignal(grp, slot, bidx, tid);
      // opart(t=p-1) stored AFTER flag: consumed only at epilogue; drain is
      // covered by the next phase's xsignal waitcnt-before-flag.
      if (ln == 0){
        const int base = ((wg4w*TP + (p-1))*32)*4;
        st_f4(rop, base + quad*16, po4[0]);
        st_f4(rop, base + 64 + quad*16, po4[1]);
      }
      xwait(grp, bidx, alive, lane);
    }
  }

  // ---- drain + autoregressive predict ----
  for (int s = T_SEQ-1; s < TP; ++s){
    // opart(t=s) consumed next phase -> LATEOP (flag-covered)
    do_phase<false,true,0,true>(rh1,rh2,rop,rsq, (s&1)*HBYTES,((s+1)&1)*HBYTES,
                           0,(s&1)*HBYTES,
                           0, 0, 0.f, s, lA1, lA2, wf1,wfx,wfh,
                           b1,b2,wx,wl, c1v,c2v, po4,
                           rowbase, grp, wg4w, tid, ln, quad, hcb);
    ++bidx; xsignal(grp, slot, bidx, tid);
    xwait(grp, bidx, alive, lane);
    if (s + 1 < TP){
      do_phase<true,false,1,false>(rh1,rh2,rop,rsq, (s&1)*HBYTES,0,
                             ((s+1)&1)*HBYTES,0,
                             0, s, blv, -1, lA1, lA2, wf1,wfx,wfh,
                             b1,b2,wx,wl, c1v,c2v, po4,
                             rowbase, grp, wg4w, tid, ln, quad, hcb);
      ++bidx; xsignal(grp, slot, bidx, tid);
      xwait(grp, bidx, alive, lane);
    }
  }

  // ---- epilogue: out[row][t] = sum over this group's 128 (slot',w') ----
  {
    float* lred = (float*)lA1;           // reuse staging LDS
    const int row = tid & 31, part = tid >> 5;
    for (int i = 0; i < 17; ++i){
      const int t = slot + i*32;
      float s = 0.f;
      #pragma unroll
      for (int q = 0; q < 16; ++q){
        const int jj = part*16 + q;      // 0..127
        const int j  = ((jj>>2)*8 + grp)*4 + (jj&3);
        s += ld_f(rop, ((j*TP + t)*32 + row)*4);
      }
      __syncthreads();
      lred[part*32 + row] = s;
      __syncthreads();
      if (tid < 32){
        float o = 0.f;
        #pragma unroll
        for (int p2 = 0; p2 < 8; ++p2) o += lred[p2*32 + tid];
        out[(rowbase + tid)*TP + t] = o + blv;
      }
    }
  }
}

extern "C" void kernel_launch(void* const* d_in, const int* in_sizes, int n_in,
                              void* d_out, int out_size, void* d_ws, size_t ws_size,
                              hipStream_t stream) {
  const float* seq = (const float*)d_in[0];
  // d_in[1] = predict (=32, hardcoded)
  const float* Wx1 = (const float*)d_in[2];
  const float* bx1 = (const float*)d_in[3];
  const float* Wh1 = (const float*)d_in[4];
  const float* bh1 = (const float*)d_in[5];
  const float* Wx2 = (const float*)d_in[6];
  const float* bx2 = (const float*)d_in[7];
  const float* Wh2 = (const float*)d_in[8];
  const float* bh2 = (const float*)d_in[9];
  const float* Wl  = (const float*)d_in[10];
  const float* bl  = (const float*)d_in[11];
  float* out = (float*)d_out;

  reset_kernel<<<1, 256, 0, stream>>>();

  sinernn_kernel<<<dim3(GRID), dim3(BLOCK), 0, stream>>>(
      seq, Wx1, bx1, Wh1, bh1, Wx2, bx2, Wh2, bh2, Wl, bl, out);
}

// Round 4
// 6620.896 us; speedup vs baseline: 2.3561x; 1.1555x over previous
//
#include <hip/hip_runtime.h>

// ---------------- problem constants ----------------
#define T_SEQ 512
#define P_PRED 32
#define TP 544            // T_SEQ + P_PRED
#define BATCH 256
#define H 512
#define G4H 2048
// ---------------- kernel config --------------------
// ROUND-0 structure byte-for-byte: 256 WGs = 8 row-groups x 32 col-slots.
// group = blockIdx&7. Group g owns batch rows [32g,32g+32). Slot s owns
// h-cols [16s,16s+16); wave w owns h-cols 16s+4w..+4 (16 gate-cols).
// Weights in VGPRs (192/lane). Per phase each WG stages its group's h
// slices ->LDS once, MFMAs from LDS. Barrier = sense flags (wave-0 poll).
// ROUND-4 change (ONE variable): all cross-WG DATA traffic (h1,h2,opart,
// seqT) uses CPol SC0 only -> coherence point = the XCD's L2, not the LIC.
// Valid because grp = wg&7 and blockIdx round-robins across the 8 XCDs, so
// all 32 WGs of a group share one XCD/L2; every producer-consumer pair in
// this kernel is intra-group. Flags stay agent-scope (LIC) -> the barrier
// itself is placement-independent; only data freshness bets on placement.
// If placement is wrong this FAILS absmax (tripwire), it cannot hang.
#define GRID 256
#define BLOCK 256
#define HBUF (BATCH*H)      // elements per h double-buffer slot
#define HBYTES (HBUF*2)
#define SCX 1               // CPol: SC0 -> bypass L1, coherent at XCD L2

typedef _Float16 half8 __attribute__((ext_vector_type(8)));
typedef float floatx4 __attribute__((ext_vector_type(4)));
typedef __amdgpu_buffer_rsrc_t rsrc_t;

#define MFMA(a,b,c) __builtin_amdgcn_mfma_f32_16x16x32_f16((a),(b),(c),0,0,0)

// ---------------- device-global state --------------
__device__ __attribute__((aligned(128))) _Float16 g_h1[2*HBUF];
__device__ __attribute__((aligned(128))) _Float16 g_h2[2*HBUF];
// o partials: [j = wg*4 + wave][t][32 group-local rows] -> full-line writes
__device__ __attribute__((aligned(128))) float g_opart[(size_t)1024*TP*32];
__device__ __attribute__((aligned(128))) float g_seqT[T_SEQ*BATCH];  // [t][row]
__device__ __attribute__((aligned(128))) unsigned g_flags[8*32];     // 1 line/group

__device__ __forceinline__ rsrc_t mkrsrc(void* p){
  return __builtin_amdgcn_make_buffer_rsrc(p, (short)0, -1, 0x00020000);
}
__device__ __forceinline__ half8 ld_h8(rsrc_t r, int off){
  auto v = __builtin_amdgcn_raw_buffer_load_b128(r, off, 0, SCX);
  return __builtin_bit_cast(half8, v);
}
__device__ __forceinline__ floatx4 ld_f4(rsrc_t r, int off){
  auto v = __builtin_amdgcn_raw_buffer_load_b128(r, off, 0, SCX);
  return __builtin_bit_cast(floatx4, v);
}
__device__ __forceinline__ float ld_f(rsrc_t r, int off){
  auto v = __builtin_amdgcn_raw_buffer_load_b32(r, off, 0, SCX);
  return __builtin_bit_cast(float, v);
}
__device__ __forceinline__ void st_f(rsrc_t r, int off, float v){
  __builtin_amdgcn_raw_buffer_store_b32(__builtin_bit_cast(unsigned, v), r, off, 0, SCX);
}
__device__ __forceinline__ void st_f4(rsrc_t r, int off, floatx4 v){
  __builtin_amdgcn_raw_buffer_store_b128(v, r, off, 0, SCX);
}

__device__ __forceinline__ float sigm(float x){ return 1.0f/(1.0f + __expf(-x)); }
__device__ __forceinline__ float tanh_f(float x){ return 1.0f - 2.0f/(1.0f + __expf(2.0f*x)); }

// Sense-flag group barrier. Release: vmcnt drain (data stores acked at L2) +
// __syncthreads; then each WG plain-stores the phase number to its own flag
// slot (agent scope, LIC). Wave 0 polls: one load covers the whole 32-slot
// flag line (lane&31 -> flag), ballot checks all >= target. Monotone phase
// numbers -> no reset/sense flip needed. Spin guard prevents hangs.
__device__ __forceinline__ void xbar(int grp, int slot, unsigned target,
                                     bool& alive, int tid){
  __builtin_amdgcn_s_waitcnt(0);
  __syncthreads();
  if (tid < 64){
    if (tid == 0)
      __hip_atomic_store(&g_flags[grp*32 + slot], target, __ATOMIC_RELAXED,
                         __HIP_MEMORY_SCOPE_AGENT);
    if (alive){
      int guard = 0;
      for (;;){
        unsigned f = __hip_atomic_load(&g_flags[grp*32 + (tid & 31)],
                                       __ATOMIC_RELAXED, __HIP_MEMORY_SCOPE_AGENT);
        if (__ballot(f >= target) == 0xFFFFFFFFFFFFFFFFull) break;
        __builtin_amdgcn_s_sleep(1);
        if (++guard > (1<<22)){ alive = false; break; }
      }
    }
  }
  __syncthreads();
}

// One pipeline phase. Stages group h slices L2->LDS (swizzled), MFMAs from
// LDS vs VGPR weights. DOL1: h1 = lstm(x, h1prev); XSEL 0 = x from seqT,
// 1 = x from o-partial gather (+bl). DOL2: h2 = lstm(h1r, h2prev) +
// full-line o-partial store (z2 reuses the staged h1r fragments).
template<bool DOL1, bool DOL2, int XSEL>
__device__ __forceinline__ void do_phase(
    rsrc_t rh1, rsrc_t rh2, rsrc_t rop, rsrc_t rsq,
    int o_h1r, int o_h2r, int o_h1w, int o_h2w,
    int o_x, int xs_t, float xadd, int t_out,
    _Float16* __restrict__ lA1, _Float16* __restrict__ lA2,
    const half8 (&wf1)[16], const half8 (&wfx)[16], const half8 (&wfh)[16],
    float b1, float b2, float wx, float wl,
    float (&c1v)[2][4], float (&c2v)[2][4],
    int rowbase, int grp, int wg4w, int tid, int ln, int quad, int hcb)
{
  // ---- stage A slices (32 rows x 512 fp16) from L2 into swizzled LDS ----
  {
    const int row = tid >> 3, c8 = tid & 7;
    const int gb1 = o_h1r + (rowbase + row)*H*2;
    const int gb2 = o_h2r + (rowbase + row)*H*2;
    #pragma unroll
    for (int g8 = 0; g8 < 8; ++g8){
      const int gran = c8*8 + g8;
      const int loff = row*512 + ((gran ^ (row&7)) << 3);
      half8 v = ld_h8(rh1, gb1 + gran*16);
      *(half8*)(lA1 + loff) = v;
      if (DOL2){
        half8 u = ld_h8(rh2, gb2 + gran*16);
        *(half8*)(lA2 + loff) = u;
      }
    }
  }

  float xv[2][4];
  if (DOL1){
    #pragma unroll
    for (int mt=0; mt<2; ++mt){
      if (XSEL == 0){
        floatx4 x4 = ld_f4(rsq, o_x + (rowbase + mt*16 + quad*4)*4);
        #pragma unroll
        for (int r=0; r<4; ++r) xv[mt][r] = x4[r] + xadd;
      } else {
        #pragma unroll
        for (int r=0; r<4; ++r){
          const int lr = mt*16 + quad*4 + r;   // group-local row
          float s = 0.f;
          #pragma unroll
          for (int cc=0; cc<8; ++cc){
            const int jj = ln*8 + cc;          // 0..127 over (slot',w')
            const int j  = ((jj>>2)*8 + grp)*4 + (jj&3);
            s += ld_f(rop, ((j*TP + xs_t)*32 + lr)*4);
          }
          s += __shfl_xor(s, 1, 64);
          s += __shfl_xor(s, 2, 64);
          s += __shfl_xor(s, 4, 64);
          s += __shfl_xor(s, 8, 64);
          xv[mt][r] = s + xadd;
        }
      }
    }
  }
  __syncthreads();   // staging visible WG-wide

  floatx4 z1[2], z2[2];
  floatx4 zf4 = {0.f,0.f,0.f,0.f};
  z1[0]=zf4; z1[1]=zf4; z2[0]=zf4; z2[1]=zf4;

  #pragma unroll
  for (int kk = 0; kk < 16; ++kk){
    const int sw = (((kk*4 + quad) ^ (ln&7)) << 3);
    half8 a10 = *(const half8*)(lA1 + ln*512 + sw);
    half8 a11 = *(const half8*)(lA1 + (16+ln)*512 + sw);
    if (DOL1){
      z1[0] = MFMA(a10, wf1[kk], z1[0]);
      z1[1] = MFMA(a11, wf1[kk], z1[1]);
    }
    if (DOL2){
      z2[0] = MFMA(a10, wfx[kk], z2[0]);
      z2[1] = MFMA(a11, wfx[kk], z2[1]);
      half8 a20 = *(const half8*)(lA2 + ln*512 + sw);
      half8 a21 = *(const half8*)(lA2 + (16+ln)*512 + sw);
      z2[0] = MFMA(a20, wfh[kk], z2[0]);
      z2[1] = MFMA(a21, wfh[kk], z2[1]);
    }
  }

  const bool l4 = (ln < 4);
  const bool evn = ((ln & 1) == 0);
  if (DOL1){
    #pragma unroll
    for (int mt=0; mt<2; ++mt){
      #pragma unroll
      for (int r=0; r<4; ++r){
        const int row = rowbase + mt*16 + quad*4 + r;
        float z = z1[mt][r] + xv[mt][r]*wx + b1;
        float p4  = __shfl_xor(z, 4, 64);
        float p8  = __shfl_xor(z, 8, 64);
        float p12 = __shfl_xor(z, 12, 64);
        float ig = sigm(z), fg = sigm(p4), og = sigm(p8), gg = tanh_f(p12);
        float c = fg*c1v[mt][r] + ig*gg;
        c1v[mt][r] = c;
        float h = og*tanh_f(c);
        unsigned hu = (unsigned)__builtin_bit_cast(unsigned short, (_Float16)h);
        unsigned pn = (unsigned)__shfl_xor((int)hu, 1, 64);
        if (l4 && evn)
          st_f(rh1, o_h1w + (row*H + hcb + ln)*2,
               __builtin_bit_cast(float, hu | (pn<<16)));
      }
    }
  }
  if (DOL2){
    floatx4 po4[2];
    #pragma unroll
    for (int mt=0; mt<2; ++mt){
      #pragma unroll
      for (int r=0; r<4; ++r){
        const int row = rowbase + mt*16 + quad*4 + r;
        float z = z2[mt][r] + b2;
        float p4  = __shfl_xor(z, 4, 64);
        float p8  = __shfl_xor(z, 8, 64);
        float p12 = __shfl_xor(z, 12, 64);
        float ig = sigm(z), fg = sigm(p4), og = sigm(p8), gg = tanh_f(p12);
        float c = fg*c2v[mt][r] + ig*gg;
        c2v[mt][r] = c;
        float h = og*tanh_f(c);
        unsigned hu = (unsigned)__builtin_bit_cast(unsigned short, (_Float16)h);
        unsigned pn = (unsigned)__shfl_xor((int)hu, 1, 64);
        if (l4 && evn)
          st_f(rh2, o_h2w + (row*H + hcb + ln)*2,
               __builtin_bit_cast(float, hu | (pn<<16)));
        float po = l4 ? h*wl : 0.f;
        po += __shfl_xor(po, 1, 64);
        po += __shfl_xor(po, 2, 64);
        po4[mt][r] = po;              // valid in ln==0 lanes
      }
    }
    if (ln == 0){                     // full 128B line per wave per t
      const int base = ((wg4w*TP + t_out)*32)*4;
      st_f4(rop, base + quad*16, po4[0]);
      st_f4(rop, base + 64 + quad*16, po4[1]);
    }
  }
}

__global__ void reset_kernel(){
  if (threadIdx.x < 8*32)
    __hip_atomic_store(&g_flags[threadIdx.x], 0u, __ATOMIC_RELAXED,
                       __HIP_MEMORY_SCOPE_AGENT);
}

__global__ __launch_bounds__(BLOCK, 1) void sinernn_kernel(
    const float* __restrict__ seq, const float* __restrict__ Wx1,
    const float* __restrict__ bx1, const float* __restrict__ Wh1,
    const float* __restrict__ bh1, const float* __restrict__ Wx2,
    const float* __restrict__ bx2, const float* __restrict__ Wh2,
    const float* __restrict__ bh2, const float* __restrict__ Wl,
    const float* __restrict__ bl,  float* __restrict__ out)
{
  __shared__ __attribute__((aligned(16))) _Float16 lA1[32*512];  // 32 KB
  __shared__ __attribute__((aligned(16))) _Float16 lA2[32*512];  // 32 KB

  const int tid  = threadIdx.x;
  const int wg   = blockIdx.x;
  const int grp  = wg & 7;             // row group 0..7 == XCD id
  const int slot = wg >> 3;            // 0..31 within group
  const int w    = tid >> 6;
  const int lane = tid & 63;
  const int ln   = lane & 15;
  const int quad = lane >> 4;
  const int rowbase = grp*32;
  const int hcb  = slot*16 + w*4;      // this wave's 4 h-cols
  const int wg4w = wg*4 + w;           // o-partial line owner id

  rsrc_t rh1 = mkrsrc((void*)&g_h1[0]);
  rsrc_t rh2 = mkrsrc((void*)&g_h2[0]);
  rsrc_t rop = mkrsrc((void*)&g_opart[0]);
  rsrc_t rsq = mkrsrc((void*)&g_seqT[0]);

  // gate-col: gate = ln>>2, h-col = hcb + (ln&3)
  const int gc = (ln>>2)*H + hcb + (ln&3);

  // ---- prologue: seqT transpose (this WG: 16 t-values x group rows) ----
  for (int i = tid; i < 16*32; i += BLOCK){
    int t = slot*16 + (i>>5), j = i & 31;
    st_f(rsq, (t*BATCH + rowbase + j)*4, seq[(rowbase+j)*T_SEQ + t]);
  }
  // zero h(-1) (buffer 1) for group rows; redundant across slots, benign
  for (int i = tid; i < 32*H/2; i += BLOCK){
    int off = HBYTES + rowbase*H*2 + i*4;
    st_f(rh1, off, 0.f);
    st_f(rh2, off, 0.f);
  }

  // ---- stage all three weight slices into VGPRs (192/lane) ----
  half8 wf1[16], wfx[16], wfh[16];
  #pragma unroll
  for (int kk = 0; kk < 16; ++kk){
    #pragma unroll
    for (int j = 0; j < 8; ++j){
      const int k = kk*32 + quad*8 + j;
      wf1[kk][j] = (_Float16)Wh1[k*G4H + gc];
      wfx[kk][j] = (_Float16)Wx2[k*G4H + gc];
      wfh[kk][j] = (_Float16)Wh2[k*G4H + gc];
    }
  }
  const float b1 = bx1[gc] + bh1[gc];
  const float b2 = bx2[gc] + bh2[gc];
  const float wx = Wx1[gc];
  const float wl = (ln < 4) ? Wl[hcb + (ln&3)] : 0.f;
  const float blv = bl[0];

  float c1v[2][4] = {{0.f,0.f,0.f,0.f},{0.f,0.f,0.f,0.f}};
  float c2v[2][4] = {{0.f,0.f,0.f,0.f},{0.f,0.f,0.f,0.f}};

  unsigned bidx = 0;
  bool alive = true;
  xbar(grp, slot, ++bidx, alive, tid);   // prologue visible group-wide

  // ---- main pipelined region: phase p computes h1(p) and h2(p-1) ----
  for (int p = 0; p < T_SEQ; ++p){
    const int b_h1r = ((p+1)&1)*HBYTES;
    const int b_h1w = (p&1)*HBYTES;
    if (p == 0)
      do_phase<true,false,0>(rh1,rh2,rop,rsq, b_h1r,0, b_h1w,0,
                             0, 0, 0.f, -1, lA1, lA2, wf1,wfx,wfh,
                             b1,b2,wx,wl, c1v,c2v,
                             rowbase, grp, wg4w, tid, ln, quad, hcb);
    else
      do_phase<true,true,0>(rh1,rh2,rop,rsq, b_h1r,(p&1)*HBYTES,
                            b_h1w,((p+1)&1)*HBYTES,
                            p*BATCH*4, 0, 0.f, p-1, lA1, lA2, wf1,wfx,wfh,
                            b1,b2,wx,wl, c1v,c2v,
                            rowbase, grp, wg4w, tid, ln, quad, hcb);
    xbar(grp, slot, ++bidx, alive, tid);
  }

  // ---- drain + autoregressive predict ----
  for (int s = T_SEQ-1; s < TP; ++s){
    do_phase<false,true,0>(rh1,rh2,rop,rsq, (s&1)*HBYTES,((s+1)&1)*HBYTES,
                           0,(s&1)*HBYTES,
                           0, 0, 0.f, s, lA1, lA2, wf1,wfx,wfh,
                           b1,b2,wx,wl, c1v,c2v,
                           rowbase, grp, wg4w, tid, ln, quad, hcb);
    xbar(grp, slot, ++bidx, alive, tid);
    if (s + 1 < TP){
      do_phase<true,false,1>(rh1,rh2,rop,rsq, (s&1)*HBYTES,0,
                             ((s+1)&1)*HBYTES,0,
                             0, s, blv, -1, lA1, lA2, wf1,wfx,wfh,
                             b1,b2,wx,wl, c1v,c2v,
                             rowbase, grp, wg4w, tid, ln, quad, hcb);
      xbar(grp, slot, ++bidx, alive, tid);
    }
  }

  // ---- epilogue: out[row][t] = sum over this group's 128 (slot',w') ----
  {
    float* lred = (float*)lA1;           // reuse staging LDS
    const int row = tid & 31, part = tid >> 5;
    for (int i = 0; i < 17; ++i){
      const int t = slot + i*32;
      float s = 0.f;
      #pragma unroll
      for (int q = 0; q < 16; ++q){
        const int jj = part*16 + q;      // 0..127
        const int j  = ((jj>>2)*8 + grp)*4 + (jj&3);
        s += ld_f(rop, ((j*TP + t)*32 + row)*4);
      }
      __syncthreads();
      lred[part*32 + row] = s;
      __syncthreads();
      if (tid < 32){
        float o = 0.f;
        #pragma unroll
        for (int p2 = 0; p2 < 8; ++p2) o += lred[p2*32 + tid];
        out[(rowbase + tid)*TP + t] = o + blv;
      }
    }
  }
}

extern "C" void kernel_launch(void* const* d_in, const int* in_sizes, int n_in,
                              void* d_out, int out_size, void* d_ws, size_t ws_size,
                              hipStream_t stream) {
  const float* seq = (const float*)d_in[0];
  // d_in[1] = predict (=32, hardcoded)
  const float* Wx1 = (const float*)d_in[2];
  const float* bx1 = (const float*)d_in[3];
  const float* Wh1 = (const float*)d_in[4];
  const float* bh1 = (const float*)d_in[5];
  const float* Wx2 = (const float*)d_in[6];
  const float* bx2 = (const float*)d_in[7];
  const float* Wh2 = (const float*)d_in[8];
  const float* bh2 = (const float*)d_in[9];
  const float* Wl  = (const float*)d_in[10];
  const float* bl  = (const float*)d_in[11];
  float* out = (float*)d_out;

  reset_kernel<<<1, 256, 0, stream>>>();

  sinernn_kernel<<<dim3(GRID), dim3(BLOCK), 0, stream>>>(
      seq, Wx1, bx1, Wh1, bh1, Wx2, bx2, Wh2, bh2, Wl, bl, out);
}

// Round 5
// 5311.296 us; speedup vs baseline: 2.9371x; 1.2466x over previous
//
#include <hip/hip_runtime.h>

// ---------------- problem constants ----------------
#define T_SEQ 512
#define P_PRED 32
#define TP 544            // T_SEQ + P_PRED
#define BATCH 256
#define H 512
#define G4H 2048
// ---------------- kernel config --------------------
// ROUND-5: dual-group software pipelining. 16 row-groups of 16 rows; group
// g lives on XCD g&7 (blockIdx round-robin, validated by round-4's pass).
// 256 WGs = 8 XCDs x 32 slots; WG (xcd,slot) serves BOTH groups xcd and
// xcd+8 per round: waitA,bodyA,signalA,waitB,bodyB,signalB. Each wait polls
// a flag published ~one body (~2-3us) earlier -> barrier latency hidden.
// Slot s owns h-cols [16s,16s+16); wave w owns 4 h-cols (16 gate-cols),
// weights in VGPRs (192/lane, shared by both groups). Bodies: stage group's
// 16-row h slices L2->LDS (round-2's 64B-chunk pattern), MFMA M=16 from
// LDS. All data at SC0 (XCD-L2 coherent, round-4); flags agent-scope
// atomics at LIC (placement-independent). opart full-128B lines (upper 16
// row slots zero-filled). Tripwires: FETCH>=1GB -> r1 anomaly; absmax fail
// -> protocol bug; both revert to round-4.
#define GRID 256
#define BLOCK 256
#define RPG 16              // rows per group
#define HBUF (BATCH*H)      // elements per h double-buffer slot
#define HBYTES (HBUF*2)
#define SCX 1               // CPol: SC0 -> bypass L1, coherent at XCD L2

typedef _Float16 half8 __attribute__((ext_vector_type(8)));
typedef float floatx4 __attribute__((ext_vector_type(4)));
typedef __amdgpu_buffer_rsrc_t rsrc_t;

#define MFMA(a,b,c) __builtin_amdgcn_mfma_f32_16x16x32_f16((a),(b),(c),0,0,0)

// ---------------- device-global state --------------
__device__ __attribute__((aligned(128))) _Float16 g_h1[2*HBUF];
__device__ __attribute__((aligned(128))) _Float16 g_h2[2*HBUF];
// o partials: [j = g*128 + slot*4 + w][t][32 slots (16 rows + 16 zero-fill)]
__device__ __attribute__((aligned(128))) float g_opart[(size_t)2048*TP*32];
__device__ __attribute__((aligned(128))) float g_seqT[T_SEQ*BATCH];  // [t][row]
__device__ __attribute__((aligned(128))) unsigned g_flags[16*32];    // 1 line/group

__device__ __forceinline__ rsrc_t mkrsrc(void* p){
  return __builtin_amdgcn_make_buffer_rsrc(p, (short)0, -1, 0x00020000);
}
__device__ __forceinline__ half8 ld_h8(rsrc_t r, int off){
  auto v = __builtin_amdgcn_raw_buffer_load_b128(r, off, 0, SCX);
  return __builtin_bit_cast(half8, v);
}
__device__ __forceinline__ floatx4 ld_f4(rsrc_t r, int off){
  auto v = __builtin_amdgcn_raw_buffer_load_b128(r, off, 0, SCX);
  return __builtin_bit_cast(floatx4, v);
}
__device__ __forceinline__ float ld_f(rsrc_t r, int off){
  auto v = __builtin_amdgcn_raw_buffer_load_b32(r, off, 0, SCX);
  return __builtin_bit_cast(float, v);
}
__device__ __forceinline__ void st_f(rsrc_t r, int off, float v){
  __builtin_amdgcn_raw_buffer_store_b32(__builtin_bit_cast(unsigned, v), r, off, 0, SCX);
}
__device__ __forceinline__ void st_f4(rsrc_t r, int off, floatx4 v){
  __builtin_amdgcn_raw_buffer_store_b128(v, r, off, 0, SCX);
}

__device__ __forceinline__ float sigm(float x){ return 1.0f/(1.0f + __expf(-x)); }
__device__ __forceinline__ float tanh_f(float x){ return 1.0f - 2.0f/(1.0f + __expf(2.0f*x)); }

// Release: drain stores (acked at L2) + WG rendezvous, then publish phase.
__device__ __forceinline__ void xsignal(int grp, int slot, unsigned target,
                                        int tid){
  __builtin_amdgcn_s_waitcnt(0);
  __syncthreads();
  if (tid == 0)
    __hip_atomic_store(&g_flags[grp*32 + slot], target, __ATOMIC_RELAXED,
                       __HIP_MEMORY_SCOPE_AGENT);
}

// Acquire: wave 0 polls the group's 32-slot flag line (lane&31), trailing
// __syncthreads releases the WG. Monotone phases, spin guard.
__device__ __forceinline__ void xwaitbar(int grp, unsigned target,
                                         bool& alive, int tid){
  if (tid < 64 && alive){
    int guard = 0;
    for (;;){
      unsigned f = __hip_atomic_load(&g_flags[grp*32 + (tid & 31)],
                                     __ATOMIC_RELAXED, __HIP_MEMORY_SCOPE_AGENT);
      if (__ballot(f >= target) == 0xFFFFFFFFFFFFFFFFull) break;
      __builtin_amdgcn_s_sleep(1);
      if (++guard > (1<<22)){ alive = false; break; }
    }
  }
  __syncthreads();
}

// One 16-row group phase. Stages group h slices L2->LDS (swizzled, 64B
// chunks/thread), MFMAs M=16 from LDS vs VGPR weights. DOL1: h1=lstm(x,
// h1prev); XSEL 0 = x from seqT, 1 = x from o-partial gather (+bl). DOL2:
// h2=lstm(h1r,h2prev) + full-line o-partial store (zero-filled top half).
template<bool DOL1, bool DOL2, int XSEL>
__device__ __forceinline__ void do_phase16(
    rsrc_t rh1, rsrc_t rh2, rsrc_t rop, rsrc_t rsq,
    int o_h1r, int o_h2r, int o_h1w, int o_h2w,
    int o_x, int xs_t, float xadd, int t_out,
    _Float16* __restrict__ lA1, _Float16* __restrict__ lA2,
    const half8 (&wf1)[16], const half8 (&wfx)[16], const half8 (&wfh)[16],
    float b1, float b2, float wx, float wl,
    float (&c1v)[4], float (&c2v)[4],
    int rowbase, int jbase, int jwave, int tid, int ln, int quad, int hcb)
{
  // ---- stage A slices (16 rows x 512 fp16) from L2 into swizzled LDS ----
  // 256 threads: row = tid>>4, each thread owns a contiguous 64B chunk.
  {
    const int row = tid >> 4, c16 = tid & 15;
    const int gb1 = o_h1r + (rowbase + row)*H*2;
    const int gb2 = o_h2r + (rowbase + row)*H*2;
    #pragma unroll
    for (int g4 = 0; g4 < 4; ++g4){
      const int gran = c16*4 + g4;
      const int loff = row*512 + ((gran ^ (row&7)) << 3);
      half8 v = ld_h8(rh1, gb1 + gran*16);
      *(half8*)(lA1 + loff) = v;
      if (DOL2){
        half8 u = ld_h8(rh2, gb2 + gran*16);
        *(half8*)(lA2 + loff) = u;
      }
    }
  }

  float xv[4];
  if (DOL1){
    if (XSEL == 0){
      floatx4 x4 = ld_f4(rsq, o_x + (rowbase + quad*4)*4);
      #pragma unroll
      for (int r=0; r<4; ++r) xv[r] = x4[r] + xadd;
    } else {
      #pragma unroll
      for (int r=0; r<4; ++r){
        const int lr = quad*4 + r;            // group-local row
        float s = 0.f;
        #pragma unroll
        for (int cc=0; cc<8; ++cc){
          const int j = jbase + ln*8 + cc;    // 128 owners of this group
          s += ld_f(rop, ((j*TP + xs_t)*32 + lr)*4);
        }
        s += __shfl_xor(s, 1, 64);
        s += __shfl_xor(s, 2, 64);
        s += __shfl_xor(s, 4, 64);
        s += __shfl_xor(s, 8, 64);
        xv[r] = s + xadd;
      }
    }
  }
  __syncthreads();   // staging visible WG-wide

  floatx4 zf4 = {0.f,0.f,0.f,0.f};
  floatx4 z1 = zf4, z2 = zf4;

  #pragma unroll
  for (int kk = 0; kk < 16; ++kk){
    const int sw = (((kk*4 + quad) ^ (ln&7)) << 3);
    half8 a1 = *(const half8*)(lA1 + ln*512 + sw);
    if (DOL1)
      z1 = MFMA(a1, wf1[kk], z1);
    if (DOL2){
      z2 = MFMA(a1, wfx[kk], z2);
      half8 a2 = *(const half8*)(lA2 + ln*512 + sw);
      z2 = MFMA(a2, wfh[kk], z2);
    }
  }

  const bool l4 = (ln < 4);
  const bool evn = ((ln & 1) == 0);
  if (DOL1){
    #pragma unroll
    for (int r=0; r<4; ++r){
      const int row = rowbase + quad*4 + r;
      float z = z1[r] + xv[r]*wx + b1;
      float p4  = __shfl_xor(z, 4, 64);
      float p8  = __shfl_xor(z, 8, 64);
      float p12 = __shfl_xor(z, 12, 64);
      float ig = sigm(z), fg = sigm(p4), og = sigm(p8), gg = tanh_f(p12);
      float c = fg*c1v[r] + ig*gg;
      c1v[r] = c;
      float h = og*tanh_f(c);
      unsigned hu = (unsigned)__builtin_bit_cast(unsigned short, (_Float16)h);
      unsigned pn = (unsigned)__shfl_xor((int)hu, 1, 64);
      if (l4 && evn)
        st_f(rh1, o_h1w + (row*H + hcb + ln)*2,
             __builtin_bit_cast(float, hu | (pn<<16)));
    }
  }
  if (DOL2){
    floatx4 po4;
    #pragma unroll
    for (int r=0; r<4; ++r){
      const int row = rowbase + quad*4 + r;
      float z = z2[r] + b2;
      float p4  = __shfl_xor(z, 4, 64);
      float p8  = __shfl_xor(z, 8, 64);
      float p12 = __shfl_xor(z, 12, 64);
      float ig = sigm(z), fg = sigm(p4), og = sigm(p8), gg = tanh_f(p12);
      float c = fg*c2v[r] + ig*gg;
      c2v[r] = c;
      float h = og*tanh_f(c);
      unsigned hu = (unsigned)__builtin_bit_cast(unsigned short, (_Float16)h);
      unsigned pn = (unsigned)__shfl_xor((int)hu, 1, 64);
      if (l4 && evn)
        st_f(rh2, o_h2w + (row*H + hcb + ln)*2,
             __builtin_bit_cast(float, hu | (pn<<16)));
      float po = l4 ? h*wl : 0.f;
      po += __shfl_xor(po, 1, 64);
      po += __shfl_xor(po, 2, 64);
      po4[r] = po;                  // valid in ln==0 lanes
    }
    if (ln == 0){                   // full 128B line per wave per t
      const int base = ((jwave*TP + t_out)*32)*4;
      st_f4(rop, base + quad*16, po4);
      st_f4(rop, base + 64 + quad*16, zf4);   // zero-fill rows 16..31
    }
  }
}

__global__ void reset_kernel(){
  if (threadIdx.x < 16*32)
    __hip_atomic_store(&g_flags[threadIdx.x], 0u, __ATOMIC_RELAXED,
                       __HIP_MEMORY_SCOPE_AGENT);
}

__global__ __launch_bounds__(BLOCK, 1) void sinernn_kernel(
    const float* __restrict__ seq, const float* __restrict__ Wx1,
    const float* __restrict__ bx1, const float* __restrict__ Wh1,
    const float* __restrict__ bh1, const float* __restrict__ Wx2,
    const float* __restrict__ bx2, const float* __restrict__ Wh2,
    const float* __restrict__ bh2, const float* __restrict__ Wl,
    const float* __restrict__ bl,  float* __restrict__ out)
{
  __shared__ __attribute__((aligned(16))) _Float16 lA1A[RPG*512];  // 16 KB
  __shared__ __attribute__((aligned(16))) _Float16 lA2A[RPG*512];  // 16 KB
  __shared__ __attribute__((aligned(16))) _Float16 lA1B[RPG*512];  // 16 KB
  __shared__ __attribute__((aligned(16))) _Float16 lA2B[RPG*512];  // 16 KB

  const int tid  = threadIdx.x;
  const int wg   = blockIdx.x;
  const int xcd  = wg & 7;
  const int slot = wg >> 3;            // 0..31
  const int ga   = xcd, gb = xcd + 8;  // this WG's two groups
  const int w    = tid >> 6;
  const int lane = tid & 63;
  const int ln   = lane & 15;
  const int quad = lane >> 4;
  const int rbA  = ga*RPG, rbB = gb*RPG;
  const int hcb  = slot*16 + w*4;      // this wave's 4 h-cols
  const int jA   = ga*128 + slot*4 + w;
  const int jB   = gb*128 + slot*4 + w;

  rsrc_t rh1 = mkrsrc((void*)&g_h1[0]);
  rsrc_t rh2 = mkrsrc((void*)&g_h2[0]);
  rsrc_t rop = mkrsrc((void*)&g_opart[0]);
  rsrc_t rsq = mkrsrc((void*)&g_seqT[0]);

  // gate-col: gate = ln>>2, h-col = hcb + (ln&3)
  const int gc = (ln>>2)*H + hcb + (ln&3);

  // ---- prologue: seqT transpose (16 t-values x 16 rows x 2 groups) ----
  for (int i = tid; i < 2*16*16; i += BLOCK){
    int g = i >> 8;
    int t = slot*16 + ((i>>4)&15), j = i & 15;
    int row = (g ? rbB : rbA) + j;
    st_f(rsq, (t*BATCH + row)*4, seq[row*T_SEQ + t]);
  }
  // zero h(-1) (buffer 1) for both groups' rows; redundant across slots
  for (int i = tid; i < RPG*H/2; i += BLOCK){
    st_f(rh1, HBYTES + rbA*H*2 + i*4, 0.f);
    st_f(rh2, HBYTES + rbA*H*2 + i*4, 0.f);
    st_f(rh1, HBYTES + rbB*H*2 + i*4, 0.f);
    st_f(rh2, HBYTES + rbB*H*2 + i*4, 0.f);
  }

  // ---- stage all three weight slices into VGPRs (192/lane, shared) ----
  half8 wf1[16], wfx[16], wfh[16];
  #pragma unroll
  for (int kk = 0; kk < 16; ++kk){
    #pragma unroll
    for (int j = 0; j < 8; ++j){
      const int k = kk*32 + quad*8 + j;
      wf1[kk][j] = (_Float16)Wh1[k*G4H + gc];
      wfx[kk][j] = (_Float16)Wx2[k*G4H + gc];
      wfh[kk][j] = (_Float16)Wh2[k*G4H + gc];
    }
  }
  const float b1 = bx1[gc] + bh1[gc];
  const float b2 = bx2[gc] + bh2[gc];
  const float wx = Wx1[gc];
  const float wl = (ln < 4) ? Wl[hcb + (ln&3)] : 0.f;
  const float blv = bl[0];

  float c1A[4] = {0.f,0.f,0.f,0.f}, c2A[4] = {0.f,0.f,0.f,0.f};
  float c1B[4] = {0.f,0.f,0.f,0.f}, c2B[4] = {0.f,0.f,0.f,0.f};

  bool alive = true;
  unsigned cur = 1;
  xsignal(ga, slot, 1, tid);           // prologue visible group-wide
  xsignal(gb, slot, 1, tid);

  // ---- main: round p = {phaseA(p), phaseB(p)}; phase computes h1(p),h2(p-1)
  for (int p = 0; p < T_SEQ; ++p){
    const int b_h1r = ((p+1)&1)*HBYTES;
    const int b_h1w = (p&1)*HBYTES;
    const int b_h2r = (p&1)*HBYTES;
    const int b_h2w = ((p+1)&1)*HBYTES;

    xwaitbar(ga, cur, alive, tid);
    if (p == 0)
      do_phase16<true,false,0>(rh1,rh2,rop,rsq, b_h1r,0, b_h1w,0,
                               0, 0, 0.f, -1, lA1A, lA2A, wf1,wfx,wfh,
                               b1,b2,wx,wl, c1A,c2A,
                               rbA, ga*128, jA, tid, ln, quad, hcb);
    else
      do_phase16<true,true,0>(rh1,rh2,rop,rsq, b_h1r,b_h2r, b_h1w,b_h2w,
                              p*BATCH*4, 0, 0.f, p-1, lA1A, lA2A, wf1,wfx,wfh,
                              b1,b2,wx,wl, c1A,c2A,
                              rbA, ga*128, jA, tid, ln, quad, hcb);
    xsignal(ga, slot, cur+1, tid);

    xwaitbar(gb, cur, alive, tid);
    if (p == 0)
      do_phase16<true,false,0>(rh1,rh2,rop,rsq, b_h1r,0, b_h1w,0,
                               0, 0, 0.f, -1, lA1B, lA2B, wf1,wfx,wfh,
                               b1,b2,wx,wl, c1B,c2B,
                               rbB, gb*128, jB, tid, ln, quad, hcb);
    else
      do_phase16<true,true,0>(rh1,rh2,rop,rsq, b_h1r,b_h2r, b_h1w,b_h2w,
                              p*BATCH*4, 0, 0.f, p-1, lA1B, lA2B, wf1,wfx,wfh,
                              b1,b2,wx,wl, c1B,c2B,
                              rbB, gb*128, jB, tid, ln, quad, hcb);
    xsignal(gb, slot, cur+1, tid);
    ++cur;
  }

  // ---- drain + autoregressive predict (one phase per group per round) ----
  for (int s = T_SEQ-1; s < TP; ++s){
    xwaitbar(ga, cur, alive, tid);
    do_phase16<false,true,0>(rh1,rh2,rop,rsq, (s&1)*HBYTES,((s+1)&1)*HBYTES,
                             0,(s&1)*HBYTES, 0, 0, 0.f, s,
                             lA1A, lA2A, wf1,wfx,wfh, b1,b2,wx,wl, c1A,c2A,
                             rbA, ga*128, jA, tid, ln, quad, hcb);
    xsignal(ga, slot, cur+1, tid);
    xwaitbar(gb, cur, alive, tid);
    do_phase16<false,true,0>(rh1,rh2,rop,rsq, (s&1)*HBYTES,((s+1)&1)*HBYTES,
                             0,(s&1)*HBYTES, 0, 0, 0.f, s,
                             lA1B, lA2B, wf1,wfx,wfh, b1,b2,wx,wl, c1B,c2B,
                             rbB, gb*128, jB, tid, ln, quad, hcb);
    xsignal(gb, slot, cur+1, tid);
    ++cur;

    if (s + 1 < TP){
      xwaitbar(ga, cur, alive, tid);
      do_phase16<true,false,1>(rh1,rh2,rop,rsq, (s&1)*HBYTES,0,
                               ((s+1)&1)*HBYTES,0, 0, s, blv, -1,
                               lA1A, lA2A, wf1,wfx,wfh, b1,b2,wx,wl, c1A,c2A,
                               rbA, ga*128, jA, tid, ln, quad, hcb);
      xsignal(ga, slot, cur+1, tid);
      xwaitbar(gb, cur, alive, tid);
      do_phase16<true,false,1>(rh1,rh2,rop,rsq, (s&1)*HBYTES,0,
                               ((s+1)&1)*HBYTES,0, 0, s, blv, -1,
                               lA1B, lA2B, wf1,wfx,wfh, b1,b2,wx,wl, c1B,c2B,
                               rbB, gb*128, jB, tid, ln, quad, hcb);
      xsignal(gb, slot, cur+1, tid);
      ++cur;
    }
  }
  xwaitbar(ga, cur, alive, tid);
  xwaitbar(gb, cur, alive, tid);

  // ---- epilogue: out[row][t] = sum over the group's 128 (slot',w') ----
  {
    float* lred = (float*)lA1A;          // reuse staging LDS
    const int row = tid & 15, part = tid >> 4;   // 16 parts x 8 j's
    for (int gsel = 0; gsel < 2; ++gsel){
      const int jb = (gsel ? gb : ga)*128;
      const int rb = (gsel ? rbB : rbA);
      for (int i = 0; i < 17; ++i){
        const int t = slot + i*32;
        float s = 0.f;
        #pragma unroll
        for (int q = 0; q < 8; ++q){
          const int j = jb + part*8 + q;
          s += ld_f(rop, ((j*TP + t)*32 + row)*4);
        }
        __syncthreads();
        lred[part*16 + row] = s;
        __syncthreads();
        if (tid < 16){
          float o = 0.f;
          #pragma unroll
          for (int p2 = 0; p2 < 16; ++p2) o += lred[p2*16 + tid];
          out[(rb + tid)*TP + t] = o + blv;
        }
      }
    }
  }
}

extern "C" void kernel_launch(void* const* d_in, const int* in_sizes, int n_in,
                              void* d_out, int out_size, void* d_ws, size_t ws_size,
                              hipStream_t stream) {
  const float* seq = (const float*)d_in[0];
  // d_in[1] = predict (=32, hardcoded)
  const float* Wx1 = (const float*)d_in[2];
  const float* bx1 = (const float*)d_in[3];
  const float* Wh1 = (const float*)d_in[4];
  const float* bh1 = (const float*)d_in[5];
  const float* Wx2 = (const float*)d_in[6];
  const float* bx2 = (const float*)d_in[7];
  const float* Wh2 = (const float*)d_in[8];
  const float* bh2 = (const float*)d_in[9];
  const float* Wl  = (const float*)d_in[10];
  const float* bl  = (const float*)d_in[11];
  float* out = (float*)d_out;

  reset_kernel<<<1, 512, 0, stream>>>();

  sinernn_kernel<<<dim3(GRID), dim3(BLOCK), 0, stream>>>(
      seq, Wx1, bx1, Wh1, bh1, Wx2, bx2, Wh2, bh2, Wl, bl, out);
}